// Round 12
// baseline (194.641 us; speedup 1.0000x reference)
//
#include <hip/hip_runtime.h>
#include <hip/hip_bf16.h>

#define N_EDGES 1000000
#define HID 128
#define VOC 105

// ws layout — fp16 element offsets for tables/frags, then byte-offset blobs
#define WSU_T   0                       // [105][128] T = emb@W_emb[0:128] + b_emb
#define WSU_U   (VOC * HID)             // 13440 : [105][128] U
#define WSU_W3  (2 * VOC * HID)         // 26880 : W3 B-frags, 16384 elems
#define WSU_WP  (WSU_W3 + 16384)        // 43264 : W_pair A-frags, 4096 elems
#define WSU_LDS 20480                   // W3+WP span staged to LDS (elems) = 40960 B
#define WSB_VIJ ((WSU_WP + 4096) * 2)   // byte 94720 : u16 sij[N_EDGES] = vi*105+vj (2 MB)
#define WSB_S   (WSB_VIJ + 2 * N_EDGES) // byte : f16 S[11025][128] = T[vi]+U[vj] (2.82 MB)

typedef float    f32x4 __attribute__((ext_vector_type(4)));
typedef _Float16 f16x8 __attribute__((ext_vector_type(8)));
typedef _Float16 f16x4 __attribute__((ext_vector_type(4)));

static __device__ __forceinline__ unsigned int pk2(float a, float b) {
    return __builtin_bit_cast(unsigned int, __builtin_amdgcn_cvt_pkrtz(a, b));
}

// ---------------- prep1: T/U tables + packed fragments + vocab pair pre-gather ----------------
__global__ void prep_kernel(const int*   __restrict__ xv,
                            const int*   __restrict__ ii,
                            const int*   __restrict__ jj,
                            const float* __restrict__ emb_table,
                            const float* __restrict__ W_pair,
                            const float* __restrict__ b_pair,
                            const float* __restrict__ W_emb,
                            const float* __restrict__ b_emb,
                            char* __restrict__ wsb) {
    _Float16* ws = (_Float16*)wsb;
    int b = blockIdx.x, t = threadIdx.x;
    if (b < VOC) {
        int v = b, which = t >> 7, h = t & 127;
        const float* wr = W_emb + which * HID * HID;
        const float* ev = emb_table + v * HID;
        float acc = which ? 0.f : b_emb[h];
        for (int d = 0; d < HID; ++d) acc = fmaf(ev[d], wr[d * HID + h], acc);
        ws[(which ? WSU_U : WSU_T) + v * HID + h] = (_Float16)acc;
    } else if (b < VOC + 64) {
        // W3 B-frags: K-perm matches swapped-pair-GEMM output; dense-store N-perm:
        // h_out(nf,p) = 4p+nf (nf<4) | 64+4p+(nf-4)
        int idx = (b - VOC) * 256 + t;
        int tt = idx & 7, lane = (idx >> 3) & 63, q = idx >> 9;
        int ks = q >> 3, nf = q & 7;
        int hl = 16 * (tt >> 2) + 4 * (lane >> 4) + (tt & 3);
        int k = 32 * ks + hl;
        int p = lane & 15;
        int n = (nf < 4) ? (4 * p + nf) : (64 + 4 * p + (nf - 4));
        ws[WSU_W3 + idx] = (_Float16)W_emb[(2 * HID + k) * HID + n];
    } else if (b < VOC + 64 + 16) {
        // W_pair^T A-frags, bias b_pair folded at k==16
        int idx = (b - VOC - 64) * 256 + t;
        int tt = idx & 7, lane = (idx >> 3) & 63, hf = idx >> 9;
        int k = 8 * (lane >> 4) + tt;
        int h = 16 * hf + (lane & 15);
        float v = (k < 16) ? W_pair[k * HID + h] : (k == 16 ? b_pair[h] : 0.f);
        ws[WSU_WP + idx] = (_Float16)v;
    } else {
        // pair pre-gather: sij[e] = x[i[e]]*105 + x[j[e]] as u16
        int e4 = ((b - VOC - 64 - 16) * 256 + t) * 4;
        if (e4 < N_EDGES) {
            int4 iv = *(const int4*)(ii + e4);
            int4 jv = *(const int4*)(jj + e4);
            ushort4 sv;
            sv.x = (unsigned short)(xv[iv.x] * VOC + xv[jv.x]);
            sv.y = (unsigned short)(xv[iv.y] * VOC + xv[jv.y]);
            sv.z = (unsigned short)(xv[iv.z] * VOC + xv[jv.z]);
            sv.w = (unsigned short)(xv[iv.w] * VOC + xv[jv.w]);
            *(ushort4*)(wsb + WSB_VIJ + (size_t)e4 * 2) = sv;
        }
    }
}

// ---------------- prep2: S[vi][vj] = T[vi] + U[vj] ----------------
__global__ void prep2_kernel(char* __restrict__ wsb) {
    const _Float16* ws = (const _Float16*)wsb;
    _Float16* S = (_Float16*)(wsb + WSB_S);
    int b = blockIdx.x, h = threadIdx.x;
    int vi = b / VOC, vj = b - vi * VOC;
    S[(size_t)b * HID + h] = ws[WSU_T + vi * HID + h] + ws[WSU_U + vj * HID + h];
}

// fast silu: 2 trans + 3 VALU
__device__ __forceinline__ float silu_f(float x) {
    return x * __builtin_amdgcn_rcpf(1.f + __builtin_amdgcn_exp2f(-1.44269504088896341f * x));
}

// ---------------- main: 2-tile ILP unroll, W3/WP LDS, S-table L2, NT dense stores ----------------
// (256,2): only launch-bounds variant observed safe on this toolchain (R4/R6/R7).
__global__ __launch_bounds__(256, 2) void edge_kernel(
    const float* __restrict__ pair_basis,
    const char*  __restrict__ wsb,
    float* __restrict__ out)
{
    __shared__ __align__(16) _Float16 sFr[WSU_LDS];   // W3+WP : 40960 B
    const int tid = threadIdx.x;
    {   // stage W3+WP into LDS
        const uint4* src = (const uint4*)((const _Float16*)wsb + WSU_W3);
        uint4* dst = (uint4*)sFr;
        for (int c = tid; c < (WSU_LDS * 2 / 16); c += 256) dst[c] = src[c];
    }
    const int lane = tid & 63;
    const int w    = tid >> 6;     // wave 0..3
    const int m    = lane & 15;
    const int g    = lane >> 4;

    const _Float16* sW3 = sFr;                  // 16384 elems
    const _Float16* sWP = sFr + 16384;          // 4096 elems
    const unsigned char* vijB = (const unsigned char*)(wsb + WSB_VIJ);
    const _Float16* Sg = (const _Float16*)(wsb + WSB_S);
    __syncthreads();

    const int nwt   = N_EDGES / 32;            // 31250 wave-iters of 32 edges (2 sub-tiles)
    const int wstep = (int)gridDim.x * 4;      // 2048 waves
    int wt = blockIdx.x * 4 + w;
    if (wt >= nwt) return;

    // ---- prefetch first iteration: pair + sij for both sub-tiles ----
    f32x4 p0[2], p1[2];
    unsigned long long sq[2];
    {
        int e0 = wt * 32;
        #pragma unroll
        for (int tl = 0; tl < 2; ++tl) {
            p0[tl] = (f32x4){0,0,0,0}; p1[tl] = (f32x4){0,0,0,0};
            int eb = e0 + tl * 16;
            if (g < 2) {
                const f32x4* pr = (const f32x4*)(pair_basis + (size_t)(eb + m) * 16 + g * 8);
                p0[tl] = __builtin_nontemporal_load(pr);
                p1[tl] = __builtin_nontemporal_load(pr + 1);
            }
            sq[tl] = *(const unsigned long long*)(vijB + (size_t)(eb + 4 * g) * 2);
        }
    }

    while (true) {
        const int e0 = wt * 32;
        const int nt = wt + wstep;

        // ---- issue next iteration's global loads early ----
        f32x4 q0[2], q1[2];
        unsigned long long nsq[2];
        #pragma unroll
        for (int tl = 0; tl < 2; ++tl) { q0[tl] = (f32x4){0,0,0,0}; q1[tl] = (f32x4){0,0,0,0}; nsq[tl] = 0; }
        if (nt < nwt) {
            int ne0 = nt * 32;
            #pragma unroll
            for (int tl = 0; tl < 2; ++tl) {
                int eb = ne0 + tl * 16;
                if (g < 2) {
                    const f32x4* pr = (const f32x4*)(pair_basis + (size_t)(eb + m) * 16 + g * 8);
                    q0[tl] = __builtin_nontemporal_load(pr);
                    q1[tl] = __builtin_nontemporal_load(pr + 1);
                }
                nsq[tl] = *(const unsigned long long*)(vijB + (size_t)(eb + 4 * g) * 2);
            }
        }

        // ---- issue S-row loads for BOTH sub-tiles (L2-resident; covered by pair-gemm) ----
        f16x4 slo[2][4], shi[2][4];
        #pragma unroll
        for (int tl = 0; tl < 2; ++tl) {
            #pragma unroll
            for (int r = 0; r < 4; ++r) {
                int sidx = (int)((sq[tl] >> (16 * r)) & 0xffff);
                const _Float16* Srow = Sg + (size_t)sidx * HID;
                slo[tl][r] = *(const f16x4*)(Srow + 4 * m);
                shi[tl][r] = *(const f16x4*)(Srow + 64 + 4 * m);
            }
        }

        // ---- two independent sub-tile pipelines (unrolled -> static indexing) ----
        #pragma unroll
        for (int tl = 0; tl < 2; ++tl) {
            const int eb = e0 + tl * 16;

            // B2 frag: pair^T, packed f32->f16
            f16x8 b2 = {0, 0, 0, 0, 0, 0, 0, 0};
            if (g < 2) {
                uint4 packed = {pk2(p0[tl][0], p0[tl][1]), pk2(p0[tl][2], p0[tl][3]),
                                pk2(p1[tl][0], p1[tl][1]), pk2(p1[tl][2], p1[tl][3])};
                b2 = __builtin_bit_cast(f16x8, packed);
            } else if (g == 2) {
                b2[0] = (_Float16)1.0f;   // bias row k==16
            }

            // swapped pair GEMM -> fast silu -> packed A-frags
            f16x8 a2[4];
            const f32x4 zero = {0.f, 0.f, 0.f, 0.f};
            #pragma unroll
            for (int ks = 0; ks < 4; ++ks) {
                f16x8 wpa = *(const f16x8*)(sWP + ((2 * ks) * 64 + lane) * 8);
                f16x8 wpb = *(const f16x8*)(sWP + ((2 * ks + 1) * 64 + lane) * 8);
                f32x4 dA = __builtin_amdgcn_mfma_f32_16x16x32_f16(wpa, b2, zero, 0, 0, 0);
                f32x4 dB = __builtin_amdgcn_mfma_f32_16x16x32_f16(wpb, b2, zero, 0, 0, 0);
                uint4 packed;
                packed.x = pk2(silu_f(dA[0]), silu_f(dA[1]));
                packed.y = pk2(silu_f(dA[2]), silu_f(dA[3]));
                packed.z = pk2(silu_f(dB[0]), silu_f(dB[1]));
                packed.w = pk2(silu_f(dB[2]), silu_f(dB[3]));
                a2[ks] = __builtin_bit_cast(f16x8, packed);
            }

            // widen S rows into accumulators
            f32x4 acc[8];
            #pragma unroll
            for (int r = 0; r < 4; ++r) {
                #pragma unroll
                for (int nf = 0; nf < 4; ++nf) {
                    acc[nf][r]     = (float)slo[tl][r][nf];
                    acc[4 + nf][r] = (float)shi[tl][r][nf];
                }
            }

            // main GEMM: acc += pb @ W3 (B-frags from LDS, lane-contiguous b128)
            #pragma unroll
            for (int ks = 0; ks < 4; ++ks) {
                #pragma unroll
                for (int nf = 0; nf < 8; ++nf) {
                    f16x8 bf = *(const f16x8*)(sW3 + ((ks * 8 + nf) * 64 + lane) * 8);
                    acc[nf] = __builtin_amdgcn_mfma_f32_16x16x32_f16(a2[ks], bf, acc[nf], 0, 0, 0);
                }
            }

            // epilogue: fast silu + DENSE nontemporal float4 stores
            #pragma unroll
            for (int r = 0; r < 4; ++r) {
                float* op = out + (size_t)(eb + 4 * g + r) * HID + 4 * m;
                f32x4 o0, o1;
                #pragma unroll
                for (int nf = 0; nf < 4; ++nf) {
                    o0[nf] = silu_f(acc[nf][r]);
                    o1[nf] = silu_f(acc[4 + nf][r]);
                }
                __builtin_nontemporal_store(o0, (f32x4*)op);
                __builtin_nontemporal_store(o1, (f32x4*)(op + 64));
            }
        }

        if (nt >= nwt) break;
        wt = nt;
        #pragma unroll
        for (int tl = 0; tl < 2; ++tl) {
            p0[tl] = q0[tl]; p1[tl] = q1[tl]; sq[tl] = nsq[tl];
        }
    }
}

extern "C" void kernel_launch(void* const* d_in, const int* in_sizes, int n_in,
                              void* d_out, int out_size, void* d_ws, size_t ws_size,
                              hipStream_t stream) {
    const int*   x          = (const int*)d_in[0];
    const float* pair_basis = (const float*)d_in[1];
    const int*   ii         = (const int*)d_in[2];
    const int*   jj         = (const int*)d_in[3];
    const float* emb_table  = (const float*)d_in[4];
    const float* W_pair     = (const float*)d_in[5];
    const float* b_pair     = (const float*)d_in[6];
    const float* W_emb      = (const float*)d_in[7];
    const float* b_emb      = (const float*)d_in[8];
    char* wsb = (char*)d_ws;
    float* out = (float*)d_out;

    const int ngather = (N_EDGES + 1023) / 1024;
    prep_kernel<<<VOC + 64 + 16 + ngather, 256, 0, stream>>>(
        x, ii, jj, emb_table, W_pair, b_pair, W_emb, b_emb, wsb);
    prep2_kernel<<<VOC * VOC, HID, 0, stream>>>(wsb);
    edge_kernel<<<512, 256, 0, stream>>>(pair_basis, wsb, out);
}

// Round 13
// 145.515 us; speedup vs baseline: 1.3376x; 1.3376x over previous
//
#include <hip/hip_runtime.h>
#include <hip/hip_bf16.h>

#define N_EDGES 1000000
#define HID 128
#define VOC 105

// ws layout (fp16 element offsets)
#define WSU_T   0                     // [105][128] T = emb@W_emb[0:128] + b_emb
#define WSU_U   (VOC * HID)           // 13440 : [105][128] U = emb@W_emb[128:256]
#define WSU_W3  (2 * VOC * HID)       // 26880 : W3 B-frags, 16384 elems
#define WSU_WP  (WSU_W3 + 16384)      // 43264 : W_pair A-frags (swapped gemm), 4096 elems
#define WSU_TU  (2 * VOC * HID)       // T+U contiguous span (elems) = 26880
#define WSB_VI  ((WSU_WP + 4096) * 2) // byte offset 94720 : u8 vi[N_EDGES]
#define WSB_VJ  (WSB_VI + N_EDGES)    // u8 vj[N_EDGES]

typedef float    f32x4 __attribute__((ext_vector_type(4)));
typedef _Float16 f16x8 __attribute__((ext_vector_type(8)));
typedef _Float16 f16x4 __attribute__((ext_vector_type(4)));

static __device__ __forceinline__ f16x8 as_f16x8(f32x4 v) {
    return __builtin_bit_cast(f16x8, v);
}
static __device__ __forceinline__ unsigned int pk2(float a, float b) {
    return __builtin_bit_cast(unsigned int, __builtin_amdgcn_cvt_pkrtz(a, b));
}

// ---------------- prep: tables + pre-packed fragments + vocab pre-gather ----------------
__global__ void prep_kernel(const int*   __restrict__ xv,
                            const int*   __restrict__ ii,
                            const int*   __restrict__ jj,
                            const float* __restrict__ emb_table,
                            const float* __restrict__ W_pair,
                            const float* __restrict__ b_pair,
                            const float* __restrict__ W_emb,
                            const float* __restrict__ b_emb,
                            char* __restrict__ wsb) {
    _Float16* ws = (_Float16*)wsb;
    int b = blockIdx.x, t = threadIdx.x;
    if (b < VOC) {
        // T[v][h] = emb[v]@W_emb[0:128,h] + b_emb[h];  U[v][h] = emb[v]@W_emb[128:256,h]
        int v = b, which = t >> 7, h = t & 127;
        const float* wr = W_emb + which * HID * HID;
        const float* ev = emb_table + v * HID;
        float acc = which ? 0.f : b_emb[h];
        for (int d = 0; d < HID; ++d) acc = fmaf(ev[d], wr[d * HID + h], acc);
        ws[(which ? WSU_U : WSU_T) + v * HID + h] = (_Float16)acc;
    } else if (b < VOC + 64) {
        // W3 B-frags: K-perm matches swapped-pair-GEMM output; dense-store N-perm:
        // h_out(nf,p) = 4p+nf (nf<4) | 64+4p+(nf-4)
        int idx = (b - VOC) * 256 + t;            // 0..16383
        int tt = idx & 7, lane = (idx >> 3) & 63, q = idx >> 9;
        int ks = q >> 3, nf = q & 7;
        int hl = 16 * (tt >> 2) + 4 * (lane >> 4) + (tt & 3);   // logical k within 32-block
        int k = 32 * ks + hl;
        int p = lane & 15;
        int n = (nf < 4) ? (4 * p + nf) : (64 + 4 * p + (nf - 4));
        ws[WSU_W3 + idx] = (_Float16)W_emb[(2 * HID + k) * HID + n];
    } else if (b < VOC + 64 + 16) {
        // W_pair^T A-frags (A2[h][k] = W_pair[k][h]), bias b_pair folded at k==16
        int idx = (b - VOC - 64) * 256 + t;       // 0..4095
        int tt = idx & 7, lane = (idx >> 3) & 63, hf = idx >> 9;
        int k = 8 * (lane >> 4) + tt;
        int h = 16 * hf + (lane & 15);
        float v = (k < 16) ? W_pair[k * HID + h] : (k == 16 ? b_pair[h] : 0.f);
        ws[WSU_WP + idx] = (_Float16)v;
    } else {
        // vocab pre-gather, 8 edges/thread: vi[e] = x[i[e]], vj[e] = x[j[e]] as bytes
        int e8 = ((b - VOC - 64 - 16) * 256 + t) * 8;
        #pragma unroll
        for (int half = 0; half < 2; ++half) {
            int e4 = e8 + half * 4;
            if (e4 < N_EDGES) {
                int4 iv = *(const int4*)(ii + e4);
                int4 jv = *(const int4*)(jj + e4);
                unsigned int vi = (unsigned)xv[iv.x] | ((unsigned)xv[iv.y] << 8) |
                                  ((unsigned)xv[iv.z] << 16) | ((unsigned)xv[iv.w] << 24);
                unsigned int vj = (unsigned)xv[jv.x] | ((unsigned)xv[jv.y] << 8) |
                                  ((unsigned)xv[jv.z] << 16) | ((unsigned)xv[jv.w] << 24);
                *(unsigned int*)(wsb + WSB_VI + e4) = vi;
                *(unsigned int*)(wsb + WSB_VJ + e4) = vj;
            }
        }
    }
}

// fast silu: 2 trans + 3 VALU
__device__ __forceinline__ float silu_f(float x) {
    return x * __builtin_amdgcn_rcpf(1.f + __builtin_amdgcn_exp2f(-1.44269504088896341f * x));
}

// ---------------- main: R7 champion + hoisted T/U reads (overlap pair-GEMM) ----------------
// (256,2): only launch-bounds variant observed safe on this toolchain (R4/R6/R7;
// (256,3)->84 VGPR, (256,4)/(1024,4)->64 VGPR + spill catastrophe R8/R9).
__global__ __launch_bounds__(256, 2) void edge_kernel(
    const float* __restrict__ pair_basis,
    const char*  __restrict__ wsb,
    float* __restrict__ out)
{
    __shared__ __align__(16) _Float16 sTU[WSU_TU];   // T,U : 53760 B
    const _Float16* ws = (const _Float16*)wsb;
    const int tid = threadIdx.x;
    {   // stage T/U into LDS
        const uint4* src = (const uint4*)ws;
        uint4* dst = (uint4*)sTU;
        for (int c = tid; c < (WSU_TU * 2 / 16); c += 256) dst[c] = src[c];
    }
    const int lane = tid & 63;
    const int w    = tid >> 6;     // wave 0..3
    const int m    = lane & 15;
    const int g    = lane >> 4;

    // loop-invariant operands, PINNED via opaque asm (R3: without pins the compiler
    // rematerialized these in-loop at VGPR=84 -> 775 MB HBM re-fetch)
    f32x4 wpf[8];
    #pragma unroll
    for (int hf = 0; hf < 8; ++hf)
        wpf[hf] = *(const f32x4*)(ws + WSU_WP + (hf * 64 + lane) * 8);
    f32x4 w3r[32];
    #pragma unroll
    for (int q = 0; q < 32; ++q)
        w3r[q] = *(const f32x4*)(ws + WSU_W3 + (q * 64 + lane) * 8);
    #pragma unroll
    for (int hf = 0; hf < 8; ++hf) asm volatile("" : "+v"(wpf[hf]));
    #pragma unroll
    for (int q = 0; q < 32; ++q)  asm volatile("" : "+v"(w3r[q]));
    __syncthreads();

    const _Float16* sT  = sTU;
    const _Float16* sU  = sTU + WSU_U;
    const unsigned char* viB = (const unsigned char*)(wsb + WSB_VI);
    const unsigned char* vjB = (const unsigned char*)(wsb + WSB_VJ);

    const int ntiles = N_EDGES / 64;            // 15625, 64 edges per block-tile (16/wave)
    const int gstep  = (int)gridDim.x;

    int tile = blockIdx.x;
    if (tile >= ntiles) return;

    // ---- prefetch first tile (pair: nontemporal, read-once stream) ----
    f32x4 p0 = {0,0,0,0}, p1 = {0,0,0,0};
    unsigned int viq, vjq;
    {
        int e0 = tile * 64 + w * 16;
        if (g < 2) {
            const f32x4* pr = (const f32x4*)(pair_basis + (size_t)(e0 + m) * 16 + g * 8);
            p0 = __builtin_nontemporal_load(pr);
            p1 = __builtin_nontemporal_load(pr + 1);
        }
        viq = *(const unsigned int*)(viB + e0 + 4 * g);
        vjq = *(const unsigned int*)(vjB + e0 + 4 * g);
    }

    while (true) {
        const int e0 = tile * 64 + w * 16;
        const int nt = tile + gstep;

        // ---- issue next tile's global loads early ----
        f32x4 q0 = {0,0,0,0}, q1 = {0,0,0,0};
        unsigned int nvi = 0, nvj = 0;
        if (nt < ntiles) {
            int ne0 = nt * 64 + w * 16;
            if (g < 2) {
                const f32x4* pr = (const f32x4*)(pair_basis + (size_t)(ne0 + m) * 16 + g * 8);
                q0 = __builtin_nontemporal_load(pr);
                q1 = __builtin_nontemporal_load(pr + 1);
            }
            nvi = *(const unsigned int*)(viB + ne0 + 4 * g);
            nvj = *(const unsigned int*)(vjB + ne0 + 4 * g);
        }

        // ---- HOISTED C-init source: T[vi]+U[vj] summed in f16 (LDS latency hides
        //      under the pair-GEMM below; widened to f32 only at main-GEMM time) ----
        f16x4 ssum_lo[4], ssum_hi[4];
        #pragma unroll
        for (int r = 0; r < 4; ++r) {
            int vi = (viq >> (8 * r)) & 0xff;
            int vj = (vjq >> (8 * r)) & 0xff;
            f16x4 tlo = *(const f16x4*)(sT + vi * HID + 4 * m);
            f16x4 thi = *(const f16x4*)(sT + vi * HID + 64 + 4 * m);
            f16x4 ulo = *(const f16x4*)(sU + vj * HID + 4 * m);
            f16x4 uhi = *(const f16x4*)(sU + vj * HID + 64 + 4 * m);
            ssum_lo[r] = tlo + ulo;                  // v_pk_add_f16 x2
            ssum_hi[r] = thi + uhi;
        }

        // ---- B2 frag: pair^T, packed f32->f16 ----
        f16x8 b2 = {0, 0, 0, 0, 0, 0, 0, 0};
        if (g < 2) {
            uint4 packed = {pk2(p0[0], p0[1]), pk2(p0[2], p0[3]),
                            pk2(p1[0], p1[1]), pk2(p1[2], p1[3])};
            b2 = __builtin_bit_cast(f16x8, packed);
        } else if (g == 2) {
            b2[0] = (_Float16)1.0f;   // bias row k==16
        }

        // ---- swapped pair GEMM -> fast silu -> packed A-frags (all registers) ----
        f16x8 a2[4];
        const f32x4 zero = {0.f, 0.f, 0.f, 0.f};
        #pragma unroll
        for (int ks = 0; ks < 4; ++ks) {
            f32x4 dA = __builtin_amdgcn_mfma_f32_16x16x32_f16(as_f16x8(wpf[2 * ks]),     b2, zero, 0, 0, 0);
            f32x4 dB = __builtin_amdgcn_mfma_f32_16x16x32_f16(as_f16x8(wpf[2 * ks + 1]), b2, zero, 0, 0, 0);
            uint4 packed;
            packed.x = pk2(silu_f(dA[0]), silu_f(dA[1]));
            packed.y = pk2(silu_f(dA[2]), silu_f(dA[3]));
            packed.z = pk2(silu_f(dB[0]), silu_f(dB[1]));
            packed.w = pk2(silu_f(dB[2]), silu_f(dB[3]));
            a2[ks] = __builtin_bit_cast(f16x8, packed);
        }

        // ---- widen hoisted sums into accumulators ----
        f32x4 acc[8];
        #pragma unroll
        for (int r = 0; r < 4; ++r) {
            #pragma unroll
            for (int nf = 0; nf < 4; ++nf) {
                acc[nf][r]     = (float)ssum_lo[r][nf];
                acc[4 + nf][r] = (float)ssum_hi[r][nf];
            }
        }

        // ---- main GEMM: acc += pb @ W3 (pinned register B-frags) ----
        #pragma unroll
        for (int ks = 0; ks < 4; ++ks) {
            #pragma unroll
            for (int nf = 0; nf < 8; ++nf)
                acc[nf] = __builtin_amdgcn_mfma_f32_16x16x32_f16(a2[ks], as_f16x8(w3r[ks * 8 + nf]), acc[nf], 0, 0, 0);
        }

        // ---- epilogue: fast silu + DENSE nontemporal float4 stores ----
        #pragma unroll
        for (int r = 0; r < 4; ++r) {
            float* op = out + (size_t)(e0 + 4 * g + r) * HID + 4 * m;
            f32x4 o0, o1;
            #pragma unroll
            for (int nf = 0; nf < 4; ++nf) {
                o0[nf] = silu_f(acc[nf][r]);
                o1[nf] = silu_f(acc[4 + nf][r]);
            }
            __builtin_nontemporal_store(o0, (f32x4*)op);
            __builtin_nontemporal_store(o1, (f32x4*)(op + 64));
        }

        if (nt >= ntiles) break;
        tile = nt; p0 = q0; p1 = q1; viq = nvi; vjq = nvj;
    }
}

extern "C" void kernel_launch(void* const* d_in, const int* in_sizes, int n_in,
                              void* d_out, int out_size, void* d_ws, size_t ws_size,
                              hipStream_t stream) {
    const int*   x          = (const int*)d_in[0];
    const float* pair_basis = (const float*)d_in[1];
    const int*   ii         = (const int*)d_in[2];
    const int*   jj         = (const int*)d_in[3];
    const float* emb_table  = (const float*)d_in[4];
    const float* W_pair     = (const float*)d_in[5];
    const float* b_pair     = (const float*)d_in[6];
    const float* W_emb      = (const float*)d_in[7];
    const float* b_emb      = (const float*)d_in[8];
    char* wsb = (char*)d_ws;
    float* out = (float*)d_out;

    const int ngather = (N_EDGES + 2047) / 2048;              // 489 blocks, 8 edges/thread
    prep_kernel<<<VOC + 64 + 16 + ngather, 256, 0, stream>>>(
        x, ii, jj, emb_table, W_pair, b_pair, W_emb, b_emb, wsb);
    edge_kernel<<<512, 256, 0, stream>>>(pair_basis, wsb, out);
}